// Round 3
// baseline (961.898 us; speedup 1.0000x reference)
//
#include <hip/hip_runtime.h>
#include <hip/hip_fp16.h>

// VQ codebook argmin: N=32768 queries x K=8192 codes x D=256 fp32.
// f16 hi/lo split (3 MFMA terms) => fp32-accurate dots on the matrix pipe;
// fused running argmin; XOR-swizzled LDS staging via global_load_lds(16B).
//
// R2: passed, absmax 0, vq_main 370us, MfmaUtil 51%, Occ 20% (2 blocks/CU).
// R3: occupancy 2->4 blocks/CU: merge hi|lo into one buffer per matrix
// (row = 32 hi | 32 lo halves = 8 x 16B blocks, same proven XOR swizzle),
// BK 64->32, split-K 2->4 (grid 1024), LDS 66->34.8KB, launch_bounds(256,4).

#define N_Q   32768
#define K_CB  8192
#define D_DIM 256

typedef _Float16 half8 __attribute__((ext_vector_type(8)));
typedef _Float16 half4 __attribute__((ext_vector_type(4)));
typedef float    f32x4 __attribute__((ext_vector_type(4)));

__device__ __forceinline__ void gl_lds16(const _Float16* g, _Float16* l) {
  __builtin_amdgcn_global_load_lds(
      (const __attribute__((address_space(1))) unsigned int*)g,
      (__attribute__((address_space(3))) unsigned int*)l, 16, 0, 0);
}

// ---------------- prep: z -> (hi,lo) f16, scale 2^4 ----------------
__global__ void vq_prep_z(const float* __restrict__ z,
                          _Float16* __restrict__ zh, _Float16* __restrict__ zl) {
  int i = blockIdx.x * 256 + threadIdx.x;          // 2,097,152 float4 groups
  float4 v = ((const float4*)z)[i];
  float xs[4] = {v.x * 16.0f, v.y * 16.0f, v.z * 16.0f, v.w * 16.0f};
  half4 h, l;
#pragma unroll
  for (int j = 0; j < 4; ++j) {
    _Float16 hj = (_Float16)xs[j];
    h[j] = hj;
    l[j] = (_Float16)(xs[j] - (float)hj);
  }
  ((half4*)zh)[i] = h;
  ((half4*)zl)[i] = l;
}

// ------- prep: codebook -> (hi,lo) f16 scale 2^15, plus 2^19*||e||^2 -------
__global__ void vq_prep_cb(const float* __restrict__ cb,
                           _Float16* __restrict__ eh, _Float16* __restrict__ el,
                           float* __restrict__ cbs) {
  int w = threadIdx.x >> 6, lane = threadIdx.x & 63;
  int code = blockIdx.x * 4 + w;                   // wave per code
  float4 v = ((const float4*)cb)[code * 64 + lane];
  float ss = v.x * v.x + v.y * v.y + v.z * v.z + v.w * v.w;
  float xs[4] = {v.x * 32768.0f, v.y * 32768.0f, v.z * 32768.0f, v.w * 32768.0f};
  half4 h, l;
#pragma unroll
  for (int j = 0; j < 4; ++j) {
    _Float16 hj = (_Float16)xs[j];
    h[j] = hj;
    l[j] = (_Float16)(xs[j] - (float)hj);
  }
  ((half4*)eh)[code * 64 + lane] = h;
  ((half4*)el)[code * 64 + lane] = l;
#pragma unroll
  for (int off = 1; off < 64; off <<= 1) ss += __shfl_xor(ss, off);
  if (lane == 0) cbs[code] = ss * 524288.0f;       // 2^19 = 2^4 * 2^15
}

// ---------------- main: fused GEMM + running argmin ----------------
// Block: 256 thr = 4 waves (2x2), tile 128 queries x 128 codes per ct-iter.
// Grid: 256 query-tiles x 4 K-splits = 1024 blocks (4/CU at 34.8KB LDS).
__global__ __launch_bounds__(256, 4)
void vq_main(const _Float16* __restrict__ zh, const _Float16* __restrict__ zl,
             const _Float16* __restrict__ eh, const _Float16* __restrict__ el,
             const float* __restrict__ cbs,
             unsigned long long* __restrict__ partials) {
  // One buffer per matrix: 128 rows x (32 hi | 32 lo) halves = 8 x 16B blocks
  // per row, XOR-(row&7) swizzled => ds_read_b128 bank-groups span 0..7.
  __shared__ __align__(16) _Float16 A[8192], B[8192];
  __shared__ float    redD[2][128];
  __shared__ unsigned redC[2][128];

  const int tid  = threadIdx.x;
  const int lane = tid & 63;
  const int w    = tid >> 6;
  const int q    = lane & 15;
  const int quad = lane >> 4;
  const int wrow = (w >> 1) * 64;   // wave's query-row base in tile
  const int wcol = (w & 1) * 64;    // wave's code-col base in tile

  const int qt    = blockIdx.x >> 2;
  const int split = blockIdx.x & 3;
  const int q0    = qt * 128;
  const int c0    = split * 2048;

  // Fragment LDS offsets (halves): hi block g=quad, lo block g=quad+4,
  // at row position p = g ^ (row&7); addr = row*64 + p*8.
  int offA[4][2], offB[4][2];
#pragma unroll
  for (int mt = 0; mt < 4; ++mt) {
    int ra = wrow + mt * 16 + q;
    int rb = wcol + mt * 16 + q;
    offA[mt][0] = ra * 64 + (((quad    ) ^ (ra & 7)) << 3);
    offA[mt][1] = ra * 64 + (((quad + 4) ^ (ra & 7)) << 3);
    offB[mt][0] = rb * 64 + (((quad    ) ^ (rb & 7)) << 3);
    offB[mt][1] = rb * 64 + (((quad + 4) ^ (rb & 7)) << 3);
  }

  float    rd[16];
  unsigned rc[16];
#pragma unroll
  for (int i = 0; i < 16; ++i) { rd[i] = 3.0e38f; rc[i] = 0u; }

  for (int ct = 0; ct < 16; ++ct) {
    const int crow0 = c0 + ct * 128;
    f32x4 acc[4][4];
#pragma unroll
    for (int mt = 0; mt < 4; ++mt)
#pragma unroll
      for (int nt = 0; nt < 4; ++nt)
        acc[mt][nt] = (f32x4){0.f, 0.f, 0.f, 0.f};

    for (int kk = 0; kk < 8; ++kk) {
      const int kcol = kk * 32;
      __syncthreads();  // WAR: previous iter's LDS reads done
#pragma unroll
      for (int c = 0; c < 4; ++c) {
        int bi   = (w * 4 + c) * 64 + lane;  // 16B-block index in buffer
        int row  = bi >> 3;
        int g    = (bi & 7) ^ (row & 7);     // swizzle on GLOBAL side
        int ksub = (g & 3) * 8;
        const _Float16* asrc = (g < 4 ? zh : zl)
                             + (size_t)(q0 + row) * 256 + kcol + ksub;
        const _Float16* bsrc = (g < 4 ? eh : el)
                             + (size_t)(crow0 + row) * 256 + kcol + ksub;
        int ldst = (w * 4 + c) * 512;        // wave-uniform LDS chunk base
        gl_lds16(asrc, &A[ldst]);
        gl_lds16(bsrc, &B[ldst]);
      }
      __syncthreads();  // staged data visible

      half8 ahf[4], alf[4], bhf[4], blf[4];
#pragma unroll
      for (int i = 0; i < 4; ++i) {
        ahf[i] = *(const half8*)&A[offA[i][0]];
        alf[i] = *(const half8*)&A[offA[i][1]];
        bhf[i] = *(const half8*)&B[offB[i][0]];
        blf[i] = *(const half8*)&B[offB[i][1]];
      }
#pragma unroll
      for (int mt = 0; mt < 4; ++mt)
#pragma unroll
        for (int nt = 0; nt < 4; ++nt) {
          acc[mt][nt] = __builtin_amdgcn_mfma_f32_16x16x32_f16(ahf[mt], bhf[nt], acc[mt][nt], 0, 0, 0);
          acc[mt][nt] = __builtin_amdgcn_mfma_f32_16x16x32_f16(ahf[mt], blf[nt], acc[mt][nt], 0, 0, 0);
          acc[mt][nt] = __builtin_amdgcn_mfma_f32_16x16x32_f16(alf[mt], bhf[nt], acc[mt][nt], 0, 0, 0);
        }
    }

    // Epilogue: dist = 2^19*cb_sq - 2*acc; running (min,idx) per row.
    const int cb0 = crow0 + wcol + q;
    float cbsv[4];
#pragma unroll
    for (int nt = 0; nt < 4; ++nt) cbsv[nt] = cbs[cb0 + nt * 16];
#pragma unroll
    for (int mt = 0; mt < 4; ++mt)
#pragma unroll
      for (int r = 0; r < 4; ++r) {
        float d = fmaf(-2.0f, acc[mt][0][r], cbsv[0]);
        unsigned cidx = (unsigned)cb0;
#pragma unroll
        for (int nt = 1; nt < 4; ++nt) {
          float dn = fmaf(-2.0f, acc[mt][nt][r], cbsv[nt]);
          if (dn < d) { d = dn; cidx = (unsigned)(cb0 + nt * 16); }  // strict <
        }
        int ri = mt * 4 + r;
        if (d < rd[ri]) { rd[ri] = d; rc[ri] = cidx; }
      }
  }

  // Cross-lane (16 codes) then cross-wave (2 col-halves) reduce.
#pragma unroll
  for (int ri = 0; ri < 16; ++ri) {
    float d = rd[ri]; unsigned cidx = rc[ri];
#pragma unroll
    for (int off = 1; off < 16; off <<= 1) {
      float od = __shfl_xor(d, off);
      unsigned oc = __shfl_xor(cidx, off);
      if (od < d || (od == d && oc < cidx)) { d = od; cidx = oc; }
    }
    if (q == 0) {
      int row = wrow + (ri >> 2) * 16 + quad * 4 + (ri & 3);
      redD[w & 1][row] = d;
      redC[w & 1][row] = cidx;
    }
  }
  __syncthreads();
  if (tid < 128) {
    float d0 = redD[0][tid]; unsigned cc0 = redC[0][tid];
    float d1 = redD[1][tid]; unsigned cc1 = redC[1][tid];
    if (d1 < d0 || (d1 == d0 && cc1 < cc0)) { d0 = d1; cc0 = cc1; }
    unsigned u = __float_as_uint(d0);
    u = (u & 0x80000000u) ? ~u : (u | 0x80000000u);  // orderable float
    partials[(size_t)split * N_Q + q0 + tid] = ((unsigned long long)u << 32) | cc0;
  }
}

// ---------------- final: combine 4 splits, write INT32 indices ----------------
__global__ void vq_final(const unsigned long long* __restrict__ partials,
                         int* __restrict__ out) {
  int i = blockIdx.x * 256 + threadIdx.x;  // 32768
  unsigned long long m = partials[i];
#pragma unroll
  for (int s = 1; s < 4; ++s) {
    unsigned long long v = partials[(size_t)s * N_Q + i];
    if (v < m) m = v;  // equal dist -> lower code (code in low bits)
  }
  out[i] = (int)(unsigned)(m & 0xffffffffull);
}

extern "C" void kernel_launch(void* const* d_in, const int* in_sizes, int n_in,
                              void* d_out, int out_size, void* d_ws, size_t ws_size,
                              hipStream_t stream) {
  const float* z  = (const float*)d_in[0];   // [32,32,32,256] fp32
  const float* cb = (const float*)d_in[1];   // [8192,256] fp32
  char* ws = (char*)d_ws;
  // ws layout (~41.1 MB): zh 16M | zl 16M | eh 4M | el 4M | cbs 32K | partials 1M
  _Float16* zh = (_Float16*)(ws);
  _Float16* zl = (_Float16*)(ws + (size_t)16 * 1024 * 1024);
  _Float16* eh = (_Float16*)(ws + (size_t)32 * 1024 * 1024);
  _Float16* el = (_Float16*)(ws + (size_t)36 * 1024 * 1024);
  float*    cbs = (float*)(ws + (size_t)40 * 1024 * 1024);
  unsigned long long* partials =
      (unsigned long long*)(ws + (size_t)40 * 1024 * 1024 + 65536);

  hipLaunchKernelGGL(vq_prep_z,  dim3(8192), dim3(256), 0, stream, z, zh, zl);
  hipLaunchKernelGGL(vq_prep_cb, dim3(2048), dim3(256), 0, stream, cb, eh, el, cbs);
  hipLaunchKernelGGL(vq_main,    dim3(1024), dim3(256), 0, stream,
                     zh, zl, eh, el, cbs, partials);
  hipLaunchKernelGGL(vq_final,   dim3(128),  dim3(256), 0, stream,
                     partials, (int*)d_out);
}

// Round 4
// 546.849 us; speedup vs baseline: 1.7590x; 1.7590x over previous
//
#include <hip/hip_runtime.h>
#include <hip/hip_fp16.h>

// VQ codebook argmin: N=32768 queries x K=8192 codes x D=256 fp32.
// f16 hi/lo split (3 MFMA terms) => fp32-accurate dots on the matrix pipe;
// fused running argmin; XOR-swizzled LDS; global_load_lds(16B) staging.
//
// R2: 370us, MfmaUtil 51% (16x16 MFMA, 2 barriers/kk, no prefetch).
// R3: FAILED - launch_bounds(256,4) -> 128-reg budget -> acc spills (698MB
//     scratch writes). Lesson: never force occupancy past reg arithmetic.
// R4: back to 2 blocks/CU. (a) 32x32x16 MFMA (886 vs 795 FLOP/cyc/SIMD),
//     (b) unit-pipelined K-loop: double-buffered 32KB LDS chunks, stage
//     unit u+1 before computing unit u -> barrier drain covered by compute.

#define N_Q   32768
#define K_CB  8192

// ws half-offsets (element units)
#define ZH_OFF 0u
#define ZL_OFF 8388608u    // 16MB
#define EH_OFF 16777216u   // 32MB
#define EL_OFF 18874368u   // 36MB

typedef _Float16 half8 __attribute__((ext_vector_type(8)));
typedef _Float16 half4 __attribute__((ext_vector_type(4)));
typedef float    f32x16 __attribute__((ext_vector_type(16)));

__device__ __forceinline__ void gl_lds16(const _Float16* g, _Float16* l) {
  __builtin_amdgcn_global_load_lds(
      (const __attribute__((address_space(1))) unsigned int*)g,
      (__attribute__((address_space(3))) unsigned int*)l, 16, 0, 0);
}

// ---------------- prep: z -> (hi,lo) f16, scale 2^4 ----------------
__global__ void vq_prep_z(const float* __restrict__ z,
                          _Float16* __restrict__ zh, _Float16* __restrict__ zl) {
  int i = blockIdx.x * 256 + threadIdx.x;
  float4 v = ((const float4*)z)[i];
  float xs[4] = {v.x * 16.0f, v.y * 16.0f, v.z * 16.0f, v.w * 16.0f};
  half4 h, l;
#pragma unroll
  for (int j = 0; j < 4; ++j) {
    _Float16 hj = (_Float16)xs[j];
    h[j] = hj;
    l[j] = (_Float16)(xs[j] - (float)hj);
  }
  ((half4*)zh)[i] = h;
  ((half4*)zl)[i] = l;
}

// ------- prep: codebook -> (hi,lo) f16 scale 2^15, plus 2^19*||e||^2 -------
__global__ void vq_prep_cb(const float* __restrict__ cb,
                           _Float16* __restrict__ eh, _Float16* __restrict__ el,
                           float* __restrict__ cbs) {
  int w = threadIdx.x >> 6, lane = threadIdx.x & 63;
  int code = blockIdx.x * 4 + w;
  float4 v = ((const float4*)cb)[code * 64 + lane];
  float ss = v.x * v.x + v.y * v.y + v.z * v.z + v.w * v.w;
  float xs[4] = {v.x * 32768.0f, v.y * 32768.0f, v.z * 32768.0f, v.w * 32768.0f};
  half4 h, l;
#pragma unroll
  for (int j = 0; j < 4; ++j) {
    _Float16 hj = (_Float16)xs[j];
    h[j] = hj;
    l[j] = (_Float16)(xs[j] - (float)hj);
  }
  ((half4*)eh)[code * 64 + lane] = h;
  ((half4*)el)[code * 64 + lane] = l;
#pragma unroll
  for (int off = 1; off < 64; off <<= 1) ss += __shfl_xor(ss, off);
  if (lane == 0) cbs[code] = ss * 524288.0f;   // 2^19 = 2^4 * 2^15
}

// ---------------- main: pipelined GEMM + fused argmin ----------------
// Block 256 thr = 4 waves (2x2), block tile 128q x 128c, wave 64x64
// (2x2 grid of 32x32x16 MFMA). Grid: 256 qtiles x 2 code-splits = 512.
// 256 units = 32 code-tiles x 8 K32-chunks; double-buffered 32KB LDS.
__global__ __launch_bounds__(256, 2)
void vq_main(const _Float16* __restrict__ ws,
             const float* __restrict__ cbs,
             unsigned long long* __restrict__ partials) {
  // Per buffer: A chunk 128 rows x (32 hi | 32 lo) halves, then B chunk same.
  // Row line = 8 x 16B blocks, block g at position p = g ^ (row & 7).
  __shared__ __align__(16) _Float16 S[2][16384];
  __shared__ float    redD[2][128];
  __shared__ unsigned redC[2][128];

  const int tid  = threadIdx.x;
  const int lane = tid & 63;
  const int w    = tid >> 6;
  const int wrow = (w >> 1) * 64;
  const int wcol = (w & 1) * 64;

  const int qt    = blockIdx.x >> 1;
  const int split = blockIdx.x & 1;
  const int q0    = qt * 128;
  const int c0    = split * 4096;

  // ---- staging source offsets (halves, from ws base); 8 slots/thread ----
  unsigned srcA[4], srcB[4];
#pragma unroll
  for (int c = 0; c < 4; ++c) {
    int bi = c * 256 + tid;
    int r  = bi >> 3;
    int p  = bi & 7;
    int g  = p ^ (r & 7);
    int hl = g >> 2;
    int kb = g & 3;
    srcA[c] = (hl ? ZL_OFF : ZH_OFF) + (unsigned)(q0 + r) * 256u + kb * 8;
    srcB[c] = (hl ? EL_OFF : EH_OFF) + (unsigned)(c0 + r) * 256u + kb * 8;
  }

  // ---- fragment LDS offsets (halves): [mt/nt][kk][hl] ----
  int offA[2][2][2], offB[2][2][2];
#pragma unroll
  for (int t = 0; t < 2; ++t)
#pragma unroll
    for (int kk = 0; kk < 2; ++kk)
#pragma unroll
      for (int hl = 0; hl < 2; ++hl) {
        int g  = hl * 4 + kk * 2 + (lane >> 5);
        int ra = wrow + t * 32 + (lane & 31);
        int rb = wcol + t * 32 + (lane & 31);
        offA[t][kk][hl] = ra * 64 + ((g ^ (ra & 7)) << 3);
        offB[t][kk][hl] = 8192 + rb * 64 + ((g ^ (rb & 7)) << 3);
      }

  float    rd[2][16];
  unsigned rc[2][16];
#pragma unroll
  for (int mt = 0; mt < 2; ++mt)
#pragma unroll
    for (int r = 0; r < 16; ++r) { rd[mt][r] = 3.0e38f; rc[mt][r] = 0u; }

  f32x16 acc[2][2];
#pragma unroll
  for (int mt = 0; mt < 2; ++mt)
#pragma unroll
    for (int nt = 0; nt < 2; ++nt)
#pragma unroll
      for (int r = 0; r < 16; ++r) acc[mt][nt][r] = 0.0f;

  // prologue: stage unit 0 into S[0]
  {
#pragma unroll
    for (int c = 0; c < 4; ++c) {
      gl_lds16(ws + srcA[c], &S[0][c * 2048 + w * 512]);
      gl_lds16(ws + srcB[c], &S[0][8192 + c * 2048 + w * 512]);
    }
  }
  __syncthreads();

  float cb0v = 0.f, cb1v = 0.f;

  for (int u = 0; u < 256; ++u) {
    const int kkc = u & 7;       // K32 chunk index (D dim)
    const int ct  = u >> 3;      // code-tile index

    // prefetch cbs for this ct's epilogue (latency hidden by 8 units)
    if (kkc == 0) {
      int colbase = c0 + ct * 128 + wcol + (lane & 31);
      cb0v = cbs[colbase];
      cb1v = cbs[colbase + 32];
    }

    // stage unit u+1 into the other buffer (no wait; drains at barrier
    // AFTER this unit's compute -> overlapped)
    if (u < 255) {
      int nu = u + 1;
      unsigned aoff = (unsigned)(nu & 7) * 32u;
      unsigned boff = (unsigned)(nu >> 3) * 32768u + aoff;
      _Float16* dst = S[nu & 1];
#pragma unroll
      for (int c = 0; c < 4; ++c) {
        gl_lds16(ws + srcA[c] + aoff, &dst[c * 2048 + w * 512]);
        gl_lds16(ws + srcB[c] + boff, &dst[8192 + c * 2048 + w * 512]);
      }
    }

    // compute unit u from S[u&1]
    {
      const _Float16* B = S[u & 1];
      half8 ah[2][2], al[2][2], bh[2][2], bl[2][2];
#pragma unroll
      for (int t = 0; t < 2; ++t)
#pragma unroll
        for (int kk = 0; kk < 2; ++kk) {
          ah[t][kk] = *(const half8*)&B[offA[t][kk][0]];
          al[t][kk] = *(const half8*)&B[offA[t][kk][1]];
          bh[t][kk] = *(const half8*)&B[offB[t][kk][0]];
          bl[t][kk] = *(const half8*)&B[offB[t][kk][1]];
        }
#pragma unroll
      for (int kk = 0; kk < 2; ++kk)
#pragma unroll
        for (int mt = 0; mt < 2; ++mt)
#pragma unroll
          for (int nt = 0; nt < 2; ++nt) {
            acc[mt][nt] = __builtin_amdgcn_mfma_f32_32x32x16_f16(
                ah[mt][kk], bh[nt][kk], acc[mt][nt], 0, 0, 0);
            acc[mt][nt] = __builtin_amdgcn_mfma_f32_32x32x16_f16(
                ah[mt][kk], bl[nt][kk], acc[mt][nt], 0, 0, 0);
            acc[mt][nt] = __builtin_amdgcn_mfma_f32_32x32x16_f16(
                al[mt][kk], bh[nt][kk], acc[mt][nt], 0, 0, 0);
          }
    }

    // epilogue at the end of each code-tile: fold into running (min, idx)
    if (kkc == 7) {
      int colbase = c0 + ct * 128 + wcol + (lane & 31);
#pragma unroll
      for (int mt = 0; mt < 2; ++mt)
#pragma unroll
        for (int r = 0; r < 16; ++r) {
          float d0 = fmaf(-2.0f, acc[mt][0][r], cb0v);
          float d1 = fmaf(-2.0f, acc[mt][1][r], cb1v);
          float d;
          unsigned ci;
          if (d1 < d0) { d = d1; ci = (unsigned)(colbase + 32); }
          else         { d = d0; ci = (unsigned)colbase; }
          if (d < rd[mt][r]) { rd[mt][r] = d; rc[mt][r] = ci; }
          acc[mt][0][r] = 0.0f;
          acc[mt][1][r] = 0.0f;
        }
    }

    __syncthreads();
  }

  // ---- cross-lane reduce over the 32 cols this wave's lanes hold ----
#pragma unroll
  for (int mt = 0; mt < 2; ++mt)
#pragma unroll
    for (int r = 0; r < 16; ++r) {
      float d = rd[mt][r];
      unsigned ci = rc[mt][r];
#pragma unroll
      for (int off = 1; off < 32; off <<= 1) {
        float od = __shfl_xor(d, off);
        unsigned oc = __shfl_xor(ci, off);
        if (od < d || (od == d && oc < ci)) { d = od; ci = oc; }
      }
      if ((lane & 31) == 0) {
        int row = wrow + mt * 32 + (r & 3) + 8 * (r >> 2) + 4 * (lane >> 5);
        redD[w & 1][row] = d;
        redC[w & 1][row] = ci;
      }
    }
  __syncthreads();
  if (tid < 128) {
    float d0 = redD[0][tid]; unsigned cc0 = redC[0][tid];
    float d1 = redD[1][tid]; unsigned cc1 = redC[1][tid];
    if (d1 < d0 || (d1 == d0 && cc1 < cc0)) { d0 = d1; cc0 = cc1; }
    unsigned uu = __float_as_uint(d0);
    uu = (uu & 0x80000000u) ? ~uu : (uu | 0x80000000u);  // orderable float
    partials[(size_t)split * N_Q + q0 + tid] =
        ((unsigned long long)uu << 32) | cc0;
  }
}

// ---------------- final: combine 2 splits, write INT32 indices ----------------
__global__ void vq_final(const unsigned long long* __restrict__ partials,
                         int* __restrict__ out) {
  int i = blockIdx.x * 256 + threadIdx.x;
  unsigned long long a = partials[i], b = partials[(size_t)N_Q + i];
  unsigned long long m = (b < a) ? b : a;  // equal dist -> lower code
  out[i] = (int)(unsigned)(m & 0xffffffffull);
}

extern "C" void kernel_launch(void* const* d_in, const int* in_sizes, int n_in,
                              void* d_out, int out_size, void* d_ws, size_t ws_size,
                              hipStream_t stream) {
  const float* z  = (const float*)d_in[0];   // [32,32,32,256] fp32
  const float* cb = (const float*)d_in[1];   // [8192,256] fp32
  char* ws = (char*)d_ws;
  // ws layout: zh 16M | zl 16M | eh 4M | el 4M | cbs 32K | partials 512K
  _Float16* zh = (_Float16*)(ws);
  _Float16* zl = (_Float16*)(ws + (size_t)16 * 1024 * 1024);
  _Float16* eh = (_Float16*)(ws + (size_t)32 * 1024 * 1024);
  _Float16* el = (_Float16*)(ws + (size_t)36 * 1024 * 1024);
  float*    cbs = (float*)(ws + (size_t)40 * 1024 * 1024);
  unsigned long long* partials =
      (unsigned long long*)(ws + (size_t)40 * 1024 * 1024 + 65536);

  hipLaunchKernelGGL(vq_prep_z,  dim3(8192), dim3(256), 0, stream, z, zh, zl);
  hipLaunchKernelGGL(vq_prep_cb, dim3(2048), dim3(256), 0, stream, cb, eh, el, cbs);
  hipLaunchKernelGGL(vq_main,    dim3(512),  dim3(256), 0, stream,
                     (const _Float16*)ws, cbs, partials);
  hipLaunchKernelGGL(vq_final,   dim3(128),  dim3(256), 0, stream,
                     partials, (int*)d_out);
}